// Round 3
// baseline (168.887 us; speedup 1.0000x reference)
//
#include <hip/hip_runtime.h>
#include <hip/hip_bf16.h>

#define B_  4
#define C_  256
#define C2_ 128
#define N_  4096
#define LOG2E 1.4426950408889634f

typedef unsigned short u16;
typedef __attribute__((ext_vector_type(8))) short bf16x8;  // 8 bf16 in 4 VGPRs
typedef __attribute__((ext_vector_type(4))) short s16x4;   // 4 bf16 in 2 VGPRs
typedef __attribute__((ext_vector_type(4))) float f32x4;

static __device__ __forceinline__ u16 f2bf(float f) {
    return __builtin_bit_cast(u16, __float2bfloat16(f));
}
static __device__ __forceinline__ float bf2f(u16 u) {
    return __bfloat162float(__builtin_bit_cast(__hip_bfloat16, u));
}
static __device__ __forceinline__ bf16x8 cvt8(const float* p) {
    u16 t[8];
#pragma unroll
    for (int j = 0; j < 8; ++j) t[j] = f2bf(p[j]);
    return *(const bf16x8*)t;
}
// LDS b64-pair load: rows are 8B-aligned but NOT 16B-aligned (conflict-aware
// leading dims), so b128 is illegal; two ds_read_b64 per fragment.
static __device__ __forceinline__ bf16x8 lds8(const u16* p) {
    s16x4 lo = *(const s16x4*)p;
    s16x4 hi = *(const s16x4*)(p + 4);
    return __builtin_shufflevector(lo, hi, 0, 1, 2, 3, 4, 5, 6, 7);
}

// ---------------------------------------------------------------------------
// Kernel 0 (prep): one-shot fp32 -> bf16 weight conversion into workspace.
// Wb[3][128][256] (wt, wp, wg) and Wob[256][128] (w_out). 131072 elems,
// 8 per thread -> grid 64. Removes per-block weight re-conversion that
// dominated projx/outproj (each of 512 blocks re-staged 3x64KB fp32).
// ---------------------------------------------------------------------------
__global__ __launch_bounds__(256) void prep_kernel(
    const float* __restrict__ wt, const float* __restrict__ wp,
    const float* __restrict__ wg, const float* __restrict__ wo,
    u16* __restrict__ Wb, u16* __restrict__ Wob) {
    int g = (blockIdx.x * 256 + threadIdx.x) * 8;
    const float* src;
    u16* dst;
    if (g < 3 * 32768) {
        int mat = g >> 15;
        src = (mat == 0 ? wt : mat == 1 ? wp : wg) + (g & 32767);
        dst = Wb + g;
    } else {
        src = wo + (g & 32767);
        dst = Wob + (g & 32767);
    }
    float w8[8];
    *(float4*)&w8[0] = *(const float4*)src;
    *(float4*)&w8[4] = *(const float4*)(src + 4);
    *(bf16x8*)dst = cvt8(w8);
}

// ---------------------------------------------------------------------------
// Kernel 1 (projx): fused x-transpose + 3-way MFMA projection.
// R2: weight LDS staging DELETED. B-fragments are direct 16B global loads
// from bf16 Wb (L2-hot, 8 independent loads per acc chain). Phase count per
// block: 12 barriers -> 3. LDS = x-transpose tile only (34 KB).
// Grid 512: h = bid>>8 so pair (i, i+256) shares the x tile AND the XCD
// (256 % 8 == 0 -> same round-robin slot).
// ---------------------------------------------------------------------------
#define XW 268

__global__ __launch_bounds__(256, 2) void projx_kernel(
    const float* __restrict__ x, const u16* __restrict__ Wb,
    const float* __restrict__ b_theta, const float* __restrict__ b_phi,
    const float* __restrict__ b_g,
    u16* __restrict__ Q, u16* __restrict__ K, u16* __restrict__ V) {
    __shared__ __align__(16) u16 XTs[64][XW];   // 34304 B
    u16 (*Vt)[72] = (u16(*)[72])XTs;            // [64][72] overlay after af load

    int bid = blockIdx.x;
    int h   = bid >> 8;            // c2-half (0/1)
    int r2  = bid & 255;
    int b   = r2 >> 6;
    int n0  = (r2 & 63) * 64;
    int tid = threadIdx.x;
    int wave = tid >> 6, lane = tid & 63, quad = (lane >> 4) & 3, l16 = lane & 15;

    // ---- stage + transpose x tile [256 c][64 n] fp32 -> XTs[n][c] bf16 ----
#pragma unroll
    for (int it = 0; it < 8; ++it) {
        int idx = it * 256 + tid;
        int q = idx & 15, p = idx >> 4;
        const float* r0 = x + ((size_t)b * C_ + 2 * p) * N_ + n0 + 4 * q;
        float4 v0 = *(const float4*)r0;
        float4 v1 = *(const float4*)(r0 + N_);
        const float* f0 = (const float*)&v0;
        const float* f1 = (const float*)&v1;
#pragma unroll
        for (int j = 0; j < 4; ++j) {
            unsigned pk = (unsigned)f2bf(f0[j]) | ((unsigned)f2bf(f1[j]) << 16);
            *(unsigned*)&XTs[4 * q + j][2 * p] = pk;
        }
    }
    __syncthreads();

    // A fragments: wave's 16 n-rows, resident whole kernel
    bf16x8 af[8];
#pragma unroll
    for (int ks = 0; ks < 8; ++ks)
        af[ks] = lds8(&XTs[wave * 16 + l16][ks * 32 + quad * 8]);
    __syncthreads();   // XTs fully consumed -> Vt may overlay

    const float* biases[3] = { b_theta, b_phi, b_g };

#pragma unroll
    for (int mat = 0; mat < 3; ++mat) {
        const float* bias = biases[mat];
        f32x4 acc[4];
#pragma unroll
        for (int i = 0; i < 4; ++i) acc[i] = (f32x4){0.f, 0.f, 0.f, 0.f};

#pragma unroll
        for (int ct = 0; ct < 4; ++ct) {
            const u16* wrow = Wb + mat * 32768 +
                              (size_t)(h * 64 + ct * 16 + l16) * 256 + quad * 8;
            bf16x8 bfr[8];
#pragma unroll
            for (int ks = 0; ks < 8; ++ks)
                bfr[ks] = *(const bf16x8*)(wrow + ks * 32);
#pragma unroll
            for (int ks = 0; ks < 8; ++ks)
                acc[ct] = __builtin_amdgcn_mfma_f32_16x16x32_bf16(
                    af[ks], bfr[ks], acc[ct], 0, 0, 0);
        }

        if (mat < 2) {
            u16* dst = mat == 0 ? Q : K;
            float scl = mat == 0 ? LOG2E : 1.0f;
#pragma unroll
            for (int ct = 0; ct < 4; ++ct) {
                int c2 = h * 64 + ct * 16 + l16;
                float bb = bias[c2];
#pragma unroll
                for (int r = 0; r < 4; ++r) {
                    int n = n0 + wave * 16 + quad * 4 + r;
                    dst[((size_t)b * N_ + n) * C2_ + c2] =
                        f2bf((acc[ct][r] + bb) * scl);
                }
            }
        } else {
#pragma unroll
            for (int ct = 0; ct < 4; ++ct) {
                int c2 = h * 64 + ct * 16 + l16;
                float bb = bias[c2];
#pragma unroll
                for (int r = 0; r < 4; ++r)
                    Vt[ct * 16 + l16][wave * 16 + quad * 4 + r] =
                        f2bf(acc[ct][r] + bb);
            }
        }
    }
    __syncthreads();   // all Vt writes done before cooperative read-out

    // cooperative V[b][h*64 + 0..63][n0..n0+63] write: 64 rows x 8 uint4
#pragma unroll
    for (int it = 0; it < 2; ++it) {
        int idx = it * 256 + tid;
        int row = idx >> 3, n8 = (idx & 7) * 8;
        *(uint4*)(V + ((size_t)b * C2_ + h * 64 + row) * N_ + n0 + n8) =
            *(const uint4*)&Vt[row][n8];
    }
}

// ---------------------------------------------------------------------------
// Kernel 2: flash attention, BM=128, BN=64, S=4 (proven best split).
// R2: back to the R-1 2-barrier structure (separate per-wave Psb — no alias
// barrier) but KEEPING the conflict-aware strides (R-1 had 4.7M bank-conflict
// cycles; these strides measured 1.0M). P written scalar into own-wave region
// inside the nn-loop (same-wave LDS ordering, no barrier needed).
// LDS 54784 B -> 2 blocks/CU = grid 512 capacity. exp2 fused in nn-loop
// keeps VGPR ~116 (no spills; R0's forced 64-VGPR spill cost 3x).
// ---------------------------------------------------------------------------
#define KS_LD 140
#define VS_LD 76
#define PS_LD 68

__global__ __launch_bounds__(256, 2) void attn_kernel(
    const u16* __restrict__ Q, const u16* __restrict__ K,
    const u16* __restrict__ V, u16* __restrict__ AO,
    u16* __restrict__ Opb, float* __restrict__ lsum, int nsplit) {
    const int BM = 128, BN = 64, D = C2_;
    const int per = B_ * (N_ / BM);      // 128
    int s    = blockIdx.x / per;
    int r0   = blockIdx.x % per;
    int b    = r0 / (N_ / BM);
    int m0   = (r0 % (N_ / BM)) * BM;
    int tid  = threadIdx.x;
    int wave = tid >> 6, lane = tid & 63, quad = (lane >> 4) & 3, l16 = lane & 15;

    __shared__ __align__(16) u16 Ks[BN][KS_LD];        // 17920 B
    __shared__ __align__(16) u16 Vs[C2_][VS_LD];       // 19456 B
    __shared__ __align__(16) u16 Psb[4][32][PS_LD];    // 17408 B ; total 54784
    u16* Ps = &Psb[wave][0][0];

    bf16x8 qf[2][4];
#pragma unroll
    for (int ms = 0; ms < 2; ++ms) {
        const u16* qp = Q + ((size_t)b * N_ + m0 + wave * 32 + ms * 16 + l16) * D;
#pragma unroll
        for (int kk = 0; kk < 4; ++kk)
            qf[ms][kk] = *(const bf16x8*)(qp + kk * 32 + quad * 8);
    }

    float l_r[2][4] = {{0.f, 0.f, 0.f, 0.f}, {0.f, 0.f, 0.f, 0.f}};
    f32x4 o_acc[2][8];
#pragma unroll
    for (int ms = 0; ms < 2; ++ms)
#pragma unroll
        for (int i = 0; i < 8; ++i) o_acc[ms][i] = (f32x4){0.f, 0.f, 0.f, 0.f};

    const int tiles = N_ / BN;                 // 64
    const int base = tiles / nsplit, rem = tiles % nsplit;
    const int t0 = s * base + (s < rem ? s : rem);
    const int cnt = base + (s < rem ? 1 : 0);
    const int nt0 = t0 * BN, nt1 = (t0 + cnt) * BN;

    for (int nt = nt0; nt < nt1; nt += BN) {
        const u16* kp = K + ((size_t)b * N_ + nt) * D;
#pragma unroll
        for (int it = 0; it < 4; ++it) {
            int idx = it * 256 + tid;
            int row = idx >> 4, col = (idx & 15) * 8;
            uint4 raw = *(const uint4*)(kp + row * D + col);
            *(uint2*)&Ks[row][col]     = make_uint2(raw.x, raw.y);
            *(uint2*)&Ks[row][col + 4] = make_uint2(raw.z, raw.w);
        }
#pragma unroll
        for (int it = 0; it < 4; ++it) {
            int idx = it * 256 + tid;
            int row = idx >> 3, col = (idx & 7) * 8;
            uint4 raw = *(const uint4*)(V + ((size_t)b * C2_ + row) * N_ + nt + col);
            *(uint2*)&Vs[row][col]     = make_uint2(raw.x, raw.y);
            *(uint2*)&Vs[row][col + 4] = make_uint2(raw.z, raw.w);
        }
        __syncthreads();

        // QK^T with exp2 + direct own-wave Ps writes fused per nn
#pragma unroll
        for (int nn = 0; nn < 4; ++nn) {
            f32x4 a0 = (f32x4){0.f, 0.f, 0.f, 0.f};
            f32x4 a1 = (f32x4){0.f, 0.f, 0.f, 0.f};
#pragma unroll
            for (int kk = 0; kk < 4; ++kk) {
                bf16x8 kf = lds8(&Ks[nn * 16 + l16][kk * 32 + quad * 8]);
                a0 = __builtin_amdgcn_mfma_f32_16x16x32_bf16(qf[0][kk], kf, a0, 0, 0, 0);
                a1 = __builtin_amdgcn_mfma_f32_16x16x32_bf16(qf[1][kk], kf, a1, 0, 0, 0);
            }
#pragma unroll
            for (int r = 0; r < 4; ++r) {
                float p0 = __builtin_amdgcn_exp2f(a0[r]);
                float p1 = __builtin_amdgcn_exp2f(a1[r]);
                l_r[0][r] += p0;
                l_r[1][r] += p1;
                Ps[(quad * 4 + r) * PS_LD + nn * 16 + l16]        = f2bf(p0);
                Ps[(16 + quad * 4 + r) * PS_LD + nn * 16 + l16]   = f2bf(p1);
            }
        }

#pragma unroll
        for (int ks = 0; ks < 2; ++ks) {
            bf16x8 pf0 = lds8(Ps + l16 * PS_LD + ks * 32 + quad * 8);
            bf16x8 pf1 = lds8(Ps + (16 + l16) * PS_LD + ks * 32 + quad * 8);
#pragma unroll
            for (int cs = 0; cs < 8; ++cs) {
                bf16x8 vf = lds8(&Vs[cs * 16 + l16][ks * 32 + quad * 8]);
                o_acc[0][cs] = __builtin_amdgcn_mfma_f32_16x16x32_bf16(pf0, vf, o_acc[0][cs], 0, 0, 0);
                o_acc[1][cs] = __builtin_amdgcn_mfma_f32_16x16x32_bf16(pf1, vf, o_acc[1][cs], 0, 0, 0);
            }
        }
        __syncthreads();   // all K/V reads done before next-tile restage
    }

#pragma unroll
    for (int ms = 0; ms < 2; ++ms)
#pragma unroll
        for (int r = 0; r < 4; ++r) {
            l_r[ms][r] += __shfl_xor(l_r[ms][r], 1);
            l_r[ms][r] += __shfl_xor(l_r[ms][r], 2);
            l_r[ms][r] += __shfl_xor(l_r[ms][r], 4);
            l_r[ms][r] += __shfl_xor(l_r[ms][r], 8);
        }

    if (Opb) {
#pragma unroll
        for (int ms = 0; ms < 2; ++ms) {
#pragma unroll
            for (int cs = 0; cs < 8; ++cs)
#pragma unroll
                for (int r = 0; r < 4; ++r) {
                    size_t row = (size_t)s * (B_ * N_) + (size_t)b * N_ +
                                 m0 + wave * 32 + ms * 16 + quad * 4 + r;
                    Opb[row * C2_ + cs * 16 + l16] = f2bf(o_acc[ms][cs][r]);
                }
            if (l16 == 0)
#pragma unroll
                for (int r = 0; r < 4; ++r) {
                    size_t row = (size_t)s * (B_ * N_) + (size_t)b * N_ +
                                 m0 + wave * 32 + ms * 16 + quad * 4 + r;
                    lsum[row] = l_r[ms][r];
                }
        }
    } else {
#pragma unroll
        for (int ms = 0; ms < 2; ++ms)
#pragma unroll
            for (int cs = 0; cs < 8; ++cs)
#pragma unroll
                for (int r = 0; r < 4; ++r) {
                    float v = o_acc[ms][cs][r] / l_r[ms][r];
                    AO[((size_t)b * N_ + m0 + wave * 32 + ms * 16 + quad * 4 + r) * C2_ +
                       cs * 16 + l16] = f2bf(v);
                }
    }
}

// ---------------------------------------------------------------------------
// Kernel 3: outproj with fused split-K combine (nsplit=4).
// R2: w_out staging DELETED — af is 4 direct 16B global loads from bf16 Wob
// (L2-hot). LDS = As + Ls only (18176 B). One barrier total.
// ---------------------------------------------------------------------------
#define OW 140

__global__ __launch_bounds__(256, 4) void outproj_kernel(
    const float* __restrict__ x, const u16* __restrict__ Opb,
    const float* __restrict__ lsum, const u16* __restrict__ AO,
    const u16* __restrict__ Wob, const float* __restrict__ b_out,
    float* __restrict__ y, int nsplit) {
    __shared__ __align__(16) u16 As[64][OW];     // 17920 B
    __shared__ float Ls[64];
    int bid = blockIdx.x;
    int per_b = (C_ / 64) * (N_ / 64);   // 256
    int b   = bid / per_b;
    int rem = bid % per_b;
    int c0  = (rem / (N_ / 64)) * 64;
    int n0  = (rem % (N_ / 64)) * 64;
    int tid = threadIdx.x;
    int wave = tid >> 6, lane = tid & 63, quad = (lane >> 4) & 3, l16 = lane & 15;

    // A-frags: direct global bf16 loads (no staging round-trip)
    bf16x8 af[4];
#pragma unroll
    for (int kk = 0; kk < 4; ++kk)
        af[kk] = *(const bf16x8*)(Wob + (size_t)(c0 + wave * 16 + l16) * C2_ +
                                  kk * 32 + quad * 8);

    if (nsplit > 1) {   // grid-uniform branch
        if (tid < 64) {
            float L = 0.f;
            for (int s = 0; s < nsplit; ++s)
                L += lsum[(size_t)s * (B_ * N_) + (size_t)b * N_ + n0 + tid];
            Ls[tid] = 1.f / L;
        }
        __syncthreads();
#pragma unroll
        for (int it = 0; it < 4; ++it) {
            int idx = it * 256 + tid;
            int n = idx >> 4, c8 = (idx & 15) * 8;
            float a[8] = {0.f, 0.f, 0.f, 0.f, 0.f, 0.f, 0.f, 0.f};
            for (int s = 0; s < nsplit; ++s) {
                const u16* op = Opb +
                    ((size_t)s * (B_ * N_) + (size_t)b * N_ + n0 + n) * C2_ + c8;
                uint4 raw = *(const uint4*)op;
                const u16* rp = (const u16*)&raw;
#pragma unroll
                for (int j = 0; j < 8; ++j) a[j] += bf2f(rp[j]);
            }
            float inv = Ls[n];
            u16 o[8];
#pragma unroll
            for (int j = 0; j < 8; ++j) o[j] = f2bf(a[j] * inv);
            *(s16x4*)&As[n][c8]     = *(const s16x4*)&o[0];
            *(s16x4*)&As[n][c8 + 4] = *(const s16x4*)&o[4];
        }
    } else {
#pragma unroll
        for (int it = 0; it < 4; ++it) {
            int idx = it * 256 + tid;
            int n = idx >> 4, c8 = (idx & 15) * 8;
            uint4 raw = *(const uint4*)(AO + ((size_t)b * N_ + n0 + n) * C2_ + c8);
            *(uint2*)&As[n][c8]     = make_uint2(raw.x, raw.y);
            *(uint2*)&As[n][c8 + 4] = make_uint2(raw.z, raw.w);
        }
    }
    __syncthreads();

    f32x4 acc[4];
#pragma unroll
    for (int i = 0; i < 4; ++i) acc[i] = (f32x4){0.f, 0.f, 0.f, 0.f};

#pragma unroll
    for (int nn = 0; nn < 4; ++nn)
#pragma unroll
        for (int kk = 0; kk < 4; ++kk) {
            bf16x8 bf = lds8(&As[nn * 16 + l16][kk * 32 + quad * 8]);
            acc[nn] = __builtin_amdgcn_mfma_f32_16x16x32_bf16(af[kk], bf, acc[nn], 0, 0, 0);
        }

    int cw = c0 + wave * 16;
    float bo[4];
#pragma unroll
    for (int r = 0; r < 4; ++r) bo[r] = b_out[cw + quad * 4 + r];

#pragma unroll
    for (int nn = 0; nn < 4; ++nn)
#pragma unroll
        for (int r = 0; r < 4; ++r) {
            int c = cw + quad * 4 + r;
            size_t off = ((size_t)b * C_ + c) * N_ + n0 + nn * 16 + l16;
            y[off] = x[off] + bo[r] + acc[nn][r];
        }
}

// ---------------------------------------------------------------------------
extern "C" void kernel_launch(void* const* d_in, const int* in_sizes, int n_in,
                              void* d_out, int out_size, void* d_ws, size_t ws_size,
                              hipStream_t stream) {
    const float* x       = (const float*)d_in[0];
    const float* w_theta = (const float*)d_in[1];
    const float* b_theta = (const float*)d_in[2];
    const float* w_phi   = (const float*)d_in[3];
    const float* b_phi   = (const float*)d_in[4];
    const float* w_g     = (const float*)d_in[5];
    const float* b_g     = (const float*)d_in[6];
    const float* w_out   = (const float*)d_in[7];
    const float* b_out   = (const float*)d_in[8];
    float* y = (float*)d_out;

    const size_t SZ = (size_t)B_ * N_ * C2_;        // 2Mi elements
    u16* Q   = (u16*)d_ws;
    u16* K   = Q + SZ;
    u16* V   = K + SZ;
    u16* Wb  = V + SZ;                               // 3*128*256 bf16
    u16* Wob = Wb + 3 * 32768;                       // 256*128 bf16
    char* dyn = (char*)(Wob + 32768);
    size_t fixedB = (3 * SZ + 4 * 32768) * 2;        // 12 MiB + 256 KiB

    size_t perS = SZ * 2 + (size_t)B_ * N_ * 4;      // Opb bf16 + lsum per split

    int S;
    if      (ws_size >= fixedB + 4 * perS) S = 4;    // grid 512 (proven best)
    else if (ws_size >= fixedB + 2 * perS) S = 2;
    else                                   S = 1;

    u16*   AO  = (u16*)dyn;       // used only when S == 1
    u16*   Opb = nullptr;
    float* ls  = nullptr;
    if (S > 1) {
        Opb = (u16*)dyn;          // aliases AO (AO unused when split)
        ls  = (float*)(Opb + (size_t)S * SZ);
    }

    prep_kernel<<<64, 256, 0, stream>>>(w_theta, w_phi, w_g, w_out, Wb, Wob);
    projx_kernel<<<B_ * (N_ / 64) * 2, 256, 0, stream>>>(
        x, Wb, b_theta, b_phi, b_g, Q, K, V);
    attn_kernel<<<B_ * (N_ / 128) * S, 256, 0, stream>>>(Q, K, V, AO, Opb, ls, S);
    outproj_kernel<<<B_ * (C_ / 64) * (N_ / 64), 256, 0, stream>>>(
        x, Opb, ls, AO, Wob, b_out, y, S);
}